// Round 2
// baseline (331.506 us; speedup 1.0000x reference)
//
#include <hip/hip_runtime.h>
#include <cstdint>
#include <cstddef>

// DotProductAttention: O = softmax_q(QK^T/8 + log(mask)) @ V
// P = mask * exp(QK^T/8); L[b,k] = sum_q P; O = P @ (diag(1/L) V).
// R4: recompute scheme (no P materialization — R3's 256MiB P round-trip was a
// net loss). Both heavy kernels are BARRIER-FREE: fragments loaded directly
// from global (per-batch slices are L2-resident; LDS staging had no reuse).
// attn uses SWAPPED orientation Sc[k][q]=K·Q^T -> float4 mask loads from the
// row-major mask AND vectorized P hand-off (ds_write_b64 / ds_read_b128,
// conflict-free [64][72] pad). stats uses natural orientation + pre-transposed
// maskT (built in prep) -> float4 loads. Explicit next-step register prefetch
// in both (R3 pv_k lesson: compiler alone keeps ~0 loads in flight).
// Dispatches: prep -> stats -> vtrans -> attn (4, no memsets).

#define LSEQ 2048
#define DHEAD 64

typedef __bf16 v8bf __attribute__((ext_vector_type(8)));
typedef __bf16 v4bf __attribute__((ext_vector_type(4)));
typedef float v4f __attribute__((ext_vector_type(4)));

#define MFMA16(a, b, c) __builtin_amdgcn_mfma_f32_16x16x32_bf16(a, b, c, 0, 0, 0)

// ---- K0: cast Q (x0.125, exact) / K to bf16; zero out,Lsum; build maskT -----
__global__ __launch_bounds__(256) void prep_k(const float* __restrict__ Q,
                                              const float* __restrict__ K,
                                              const float* __restrict__ mask,
                                              __bf16* __restrict__ Qb,
                                              __bf16* __restrict__ Kb,
                                              float* __restrict__ maskT,
                                              float* __restrict__ outz,
                                              float* __restrict__ Lz) {
  const int bx = blockIdx.x;
  const int tid = threadIdx.x;
  if (bx < 2048) {
    size_t j = (size_t)bx * 256 + tid;
    size_t i = j * 4;
    float4 q = *(const float4*)(Q + i);
    float4 k = *(const float4*)(K + i);
    v4bf qo = {(__bf16)(q.x * 0.125f), (__bf16)(q.y * 0.125f),
               (__bf16)(q.z * 0.125f), (__bf16)(q.w * 0.125f)};
    v4bf ko = {(__bf16)k.x, (__bf16)k.y, (__bf16)k.z, (__bf16)k.w};
    *(v4bf*)(Qb + i) = qo;
    *(v4bf*)(Kb + i) = ko;
    float4 z = {0.f, 0.f, 0.f, 0.f};
    *(float4*)(outz + i) = z;  // out = 16*2048*64 = 2M floats = 2048*256*4
    if (j < (size_t)16 * LSEQ) Lz[j] = 0.f;
  } else {
    // transpose one 64x64 mask tile: maskT[k][q] = mask[q][k]
    __shared__ __align__(16) float tile[64][68];  // 272B rows: f4-aligned
    const int t = bx - 2048;
    const int q0t = (t & 31) * 64;
    const int k0t = (t >> 5) * 64;
#pragma unroll
    for (int p = 0; p < 4; ++p) {
      int flat = p * 1024 + tid * 4;
      int r = flat >> 6, c = flat & 63;
      float4 v = *(const float4*)(mask + (size_t)(q0t + r) * LSEQ + k0t + c);
      *(float4*)&tile[r][c] = v;
    }
    __syncthreads();
#pragma unroll
    for (int p = 0; p < 4; ++p) {
      int flat = p * 1024 + tid * 4;
      int kr = flat >> 6, qc2 = flat & 63;
      float4 o = {tile[qc2][kr], tile[qc2 + 1][kr], tile[qc2 + 2][kr],
                  tile[qc2 + 3][kr]};
      *(float4*)(maskT + (size_t)(k0t + kr) * LSEQ + q0t + qc2) = o;
    }
  }
}

// ---- K1: Lsum[b,k] += sum_q mask*exp(S). Barrier-free, natural orient. ------
// Grid: b(16) x qc(4) x kt(32); XCD = kt%8 -> 2MB maskT k-slice per XCD L2.
// C layout: row(q)=quad*4+r, col(k)=n -> maskT float4 covers the 4 q's.
__global__ __launch_bounds__(256, 4) void stats_k(const __bf16* __restrict__ Qb,
                                                  const __bf16* __restrict__ Kb,
                                                  const float* __restrict__ maskT,
                                                  float* __restrict__ Lsum) {
  const int bx = blockIdx.x;
  const int b = bx >> 7;
  const int qc = (bx >> 5) & 3;
  const int k0 = (bx & 31) * 64;
  const int tid = threadIdx.x;
  const int w = tid >> 6, lane = tid & 63;
  const int quad = lane >> 4, n = lane & 15;

  __shared__ float psum[4][64];

  // persistent K B-frags: lane n -> K row k0+sub*16+n, d = dh*32+quad*8
  v8bf bk[4][2];
#pragma unroll
  for (int sub = 0; sub < 4; ++sub)
#pragma unroll
    for (int dh = 0; dh < 2; ++dh)
      bk[sub][dh] = *(const v8bf*)(Kb + ((size_t)b * LSEQ + k0 + sub * 16 + n) * DHEAD +
                                   dh * 32 + quad * 8);

  float colsum[4] = {0.f, 0.f, 0.f, 0.f};
  const int qbeg = qc * 512;

  v8bf aq0, aq1, nq0, nq1;
  float4 m4[4], nm[4];
  {
    const __bf16* qp = Qb + ((size_t)b * LSEQ + qbeg + w * 16 + n) * DHEAD + quad * 8;
    aq0 = *(const v8bf*)qp;
    aq1 = *(const v8bf*)(qp + 32);
#pragma unroll
    for (int sub = 0; sub < 4; ++sub)
      m4[sub] = *(const float4*)(maskT + (size_t)(k0 + sub * 16 + n) * LSEQ + qbeg +
                                 w * 16 + quad * 4);
  }
#pragma unroll 1
  for (int ks = 0; ks < 8; ++ks) {
    const int qnext = qbeg + ((ks + 1) & 7) * 64;  // wraps (harmless) on last
    {
      const __bf16* qp = Qb + ((size_t)b * LSEQ + qnext + w * 16 + n) * DHEAD + quad * 8;
      nq0 = *(const v8bf*)qp;
      nq1 = *(const v8bf*)(qp + 32);
#pragma unroll
      for (int sub = 0; sub < 4; ++sub)
        nm[sub] = *(const float4*)(maskT + (size_t)(k0 + sub * 16 + n) * LSEQ + qnext +
                                   w * 16 + quad * 4);
    }
#pragma unroll
    for (int sub = 0; sub < 4; ++sub) {
      v4f c = {0.f, 0.f, 0.f, 0.f};
      c = MFMA16(aq0, bk[sub][0], c);
      c = MFMA16(aq1, bk[sub][1], c);
      colsum[sub] += m4[sub].x * __expf(c[0]) + m4[sub].y * __expf(c[1]) +
                     m4[sub].z * __expf(c[2]) + m4[sub].w * __expf(c[3]);
    }
    aq0 = nq0;
    aq1 = nq1;
#pragma unroll
    for (int sub = 0; sub < 4; ++sub) m4[sub] = nm[sub];
  }

  // reduce over quads (q-rows) then waves, one atomic burst per WG
#pragma unroll
  for (int sub = 0; sub < 4; ++sub) {
    float v = colsum[sub];
    v += __shfl_xor(v, 16);
    v += __shfl_xor(v, 32);
    if (quad == 0) psum[w][sub * 16 + n] = v;
  }
  __syncthreads();
  if (tid < 64) {
    float s = psum[0][tid] + psum[1][tid] + psum[2][tid] + psum[3][tid];
    unsafeAtomicAdd(&Lsum[(size_t)b * LSEQ + k0 + tid], s);
  }
}

// ---- K2: Vts[b][v][k] = bf16(V[b][k][v] / L[b][k]) --------------------------
__global__ __launch_bounds__(256) void vtrans_k(const float* __restrict__ V,
                                                const float* __restrict__ Lsum,
                                                __bf16* __restrict__ Vts) {
  const int b = blockIdx.x >> 6;
  const int k0 = (blockIdx.x & 63) * 32;
  const int tid = threadIdx.x;
  __shared__ float tile[32][65];
  __shared__ float invl[32];
  if (tid < 32) invl[tid] = 1.0f / Lsum[(size_t)b * LSEQ + k0 + tid];
#pragma unroll
  for (int t = 0; t < 8; ++t) {
    int flat = t * 256 + tid;
    int k = flat >> 6, v = flat & 63;
    tile[k][v] = V[((size_t)b * LSEQ + k0 + k) * DHEAD + v];
  }
  __syncthreads();
#pragma unroll
  for (int t = 0; t < 8; ++t) {
    int flat = t * 256 + tid;
    int v = flat >> 5, k = flat & 31;
    Vts[((size_t)b * DHEAD + v) * LSEQ + k0 + k] = (__bf16)(tile[k][v] * invl[k]);
  }
}

// ---- K3: O^T[v][q] += Vt' x P, swapped orientation, barrier-free ------------
// Grid: b(16) x kc(4) x qt(32); XCD = qt%8 -> 2MB mask q-row-slice per XCD L2.
// Sc[k][q]=mfma(A=K,B=Q): row(k)=quad*4+r, col(q)=n -> float4 mask loads and
// v4bf P writes. PV: D[v][q]=mfma(A=Vts,B=P): pb read as v8bf from Pt[q][k].
__global__ __launch_bounds__(256, 3) void attn_k(const __bf16* __restrict__ Qb,
                                                 const __bf16* __restrict__ Kb,
                                                 const __bf16* __restrict__ Vts,
                                                 const float* __restrict__ mask,
                                                 float* __restrict__ out) {
  const int bx = blockIdx.x;
  const int b = bx >> 7;
  const int kc = (bx >> 5) & 3;
  const int q0 = (bx & 31) * 64;
  const int tid = threadIdx.x;
  const int w = tid >> 6, lane = tid & 63;
  const int quad = lane >> 4, n = lane & 15;

  __shared__ __align__(16) __bf16 Pt[64][72];  // 144B rows: b64/b128 conflict-free

  const int qg = q0 + w * 16 + n;  // this lane's q (B column / Pt row / out row)

  // persistent B-frags (Q columns), scaled by 1/8 already
  v8bf bq[2];
#pragma unroll
  for (int dh = 0; dh < 2; ++dh)
    bq[dh] = *(const v8bf*)(Qb + ((size_t)b * LSEQ + qg) * DHEAD + dh * 32 + quad * 8);

  v4f acc[4];
#pragma unroll
  for (int vs = 0; vs < 4; ++vs) acc[vs] = (v4f){0.f, 0.f, 0.f, 0.f};

  const int kbeg = kc * 512;
  const __bf16* kbase = Kb + (size_t)b * LSEQ * DHEAD;
  const float* mbase = mask + (size_t)qg * LSEQ;

  v8bf ak[4][2];
  float4 m4[4];
#define LOAD_STEP(kb)                                                                  \
  {                                                                                    \
    _Pragma("unroll") for (int sub = 0; sub < 4; ++sub) {                              \
      _Pragma("unroll") for (int dh = 0; dh < 2; ++dh) ak[sub][dh] =                   \
          *(const v8bf*)(kbase + (size_t)((kb) + sub * 16 + n) * DHEAD + dh * 32 +     \
                         quad * 8);                                                    \
      m4[sub] = *(const float4*)(mbase + (kb) + sub * 16 + quad * 4);                  \
    }                                                                                  \
  }
  LOAD_STEP(kbeg);

#pragma unroll 1
  for (int ks = 0; ks < 8; ++ks) {
    const int kb = kbeg + ks * 64;
    // QK^T (swapped): Sc[k][q]; P = mask*exp -> bf16 -> Pt[q][k] (v4bf write)
#pragma unroll
    for (int sub = 0; sub < 4; ++sub) {
      v4f c = {0.f, 0.f, 0.f, 0.f};
      c = MFMA16(ak[sub][0], bq[0], c);
      c = MFMA16(ak[sub][1], bq[1], c);
      v4bf pv;
      pv[0] = (__bf16)(m4[sub].x * __expf(c[0]));
      pv[1] = (__bf16)(m4[sub].y * __expf(c[1]));
      pv[2] = (__bf16)(m4[sub].z * __expf(c[2]));
      pv[3] = (__bf16)(m4[sub].w * __expf(c[3]));
      *(v4bf*)&Pt[w * 16 + n][sub * 16 + quad * 4] = pv;
    }
    // V^T A-frags for this step (L2-resident, 16x64B coalesced)
    v8bf av[4][2];
#pragma unroll
    for (int vs = 0; vs < 4; ++vs)
#pragma unroll
      for (int kk = 0; kk < 2; ++kk)
        av[vs][kk] = *(const v8bf*)(Vts + ((size_t)b * DHEAD + vs * 16 + n) * LSEQ + kb +
                                    kk * 32 + quad * 8);
    // prefetch next step's K/mask while PV runs
    if (ks < 7) LOAD_STEP(kb + 64);
    __asm__ volatile("s_waitcnt lgkmcnt(0)" ::: "memory");  // own-wave P visible
    // PV: D[v][q] += Vts x P
#pragma unroll
    for (int kk = 0; kk < 2; ++kk) {
      v8bf pb = *(const v8bf*)&Pt[w * 16 + n][kk * 32 + quad * 8];
#pragma unroll
      for (int vs = 0; vs < 4; ++vs) acc[vs] = MFMA16(av[vs][kk], pb, acc[vs]);
    }
  }
#undef LOAD_STEP

  // D row = v = vs*16+quad*4+r, col = q = qg -> contiguous-in-v atomics
  float* obase = out + ((size_t)b * LSEQ + qg) * DHEAD;
#pragma unroll
  for (int vs = 0; vs < 4; ++vs)
#pragma unroll
    for (int r = 0; r < 4; ++r)
      unsafeAtomicAdd(obase + vs * 16 + quad * 4 + r, acc[vs][r]);
}

extern "C" void kernel_launch(void* const* d_in, const int* in_sizes, int n_in,
                              void* d_out, int out_size, void* d_ws, size_t ws_size,
                              hipStream_t stream) {
  const float* Q = (const float*)d_in[0];
  const float* K = (const float*)d_in[1];
  const float* V = (const float*)d_in[2];
  const float* mask = (const float*)d_in[3];
  float* out = (float*)d_out;

  char* ws = (char*)d_ws;
  // ws: Qb 4MiB | Kb 4MiB | Vts 4MiB | Lsum 128KiB | maskT 16MiB  (~28.1 MiB)
  __bf16* Qb = (__bf16*)(ws);
  __bf16* Kb = (__bf16*)(ws + (4 << 20));
  __bf16* Vts = (__bf16*)(ws + (8 << 20));
  float* Lsum = (float*)(ws + (12 << 20));
  float* maskT = (float*)(ws + (12 << 20) + (1 << 17));
  const size_t need = ((size_t)12 << 20) + (1 << 17) + (size_t)LSEQ * LSEQ * 4;
  if (ws_size < need) return;  // workspace too small — fail loudly (poison out)

  prep_k<<<3072, 256, 0, stream>>>(Q, K, mask, Qb, Kb, maskT, out, Lsum);
  stats_k<<<2048, 256, 0, stream>>>(Qb, Kb, maskT, Lsum);
  vtrans_k<<<1024, 256, 0, stream>>>(V, Lsum, Vts);
  attn_k<<<2048, 256, 0, stream>>>(Qb, Kb, Vts, mask, out);
}

// Round 3
// 189.522 us; speedup vs baseline: 1.7492x; 1.7492x over previous
//
#include <hip/hip_runtime.h>
#include <cstdint>
#include <cstddef>

// DotProductAttention: O = softmax_q(QK^T/8 + log(mask)) @ V
// P = mask * exp(QK^T/8); L[b,k] = sum_q P; O = P @ (diag(1/L) V).
// R5 = R2 structure (global_load_lds staging — R3/R4 proved direct per-lane
// fragment gathers serialize) + two fixes:
//  (a) T3-minimum pipeline: double-buffered LDS tiles, stage(t+1) issued
//      BEFORE compute(t), ONE barrier per step (R2 had 2 + zero overlap).
//  (b) swapped QK^T orientation (R4-verified): C[k][q] -> mask read is a
//      row-major float4 per sub-tile (4 loads vs R2's 16 scalar gathers),
//      prefetched one step ahead; stats colsums stay lane-resident
//      (k' = sub*16+quad*4+r fixed per lane), reduced over n once at end.
// attn PV unchanged from R2 (verified): A=P rows, B=Vt; Pt hand-off is
// v4bf writes / v8bf reads, own-wave rows only (no barrier, lgkmcnt(0)).

#define LSEQ 2048
#define DHEAD 64

typedef __bf16 v8bf __attribute__((ext_vector_type(8)));
typedef __bf16 v4bf __attribute__((ext_vector_type(4)));
typedef float v4f __attribute__((ext_vector_type(4)));

#define MFMA16(a, b, c) __builtin_amdgcn_mfma_f32_16x16x32_bf16(a, b, c, 0, 0, 0)

__device__ __forceinline__ void gl_lds16(const void* g, void* l) {
  __builtin_amdgcn_global_load_lds(
      (__attribute__((address_space(1))) void*)g,
      (__attribute__((address_space(3))) void*)l, 16, 0, 0);
}

// ---- K0: cast Q (x0.125, exact) / K to bf16; zero out and Lsum --------------
__global__ __launch_bounds__(256) void cast_qk(const float* __restrict__ Q,
                                               const float* __restrict__ K,
                                               __bf16* __restrict__ Qb,
                                               __bf16* __restrict__ Kb,
                                               float* __restrict__ outz,
                                               float* __restrict__ Lz) {
  size_t j = (size_t)blockIdx.x * 256 + threadIdx.x;
  size_t i = j * 4;
  float4 q = *(const float4*)(Q + i);
  float4 k = *(const float4*)(K + i);
  v4bf qo = {(__bf16)(q.x * 0.125f), (__bf16)(q.y * 0.125f),
             (__bf16)(q.z * 0.125f), (__bf16)(q.w * 0.125f)};
  v4bf ko = {(__bf16)k.x, (__bf16)k.y, (__bf16)k.z, (__bf16)k.w};
  *(v4bf*)(Qb + i) = qo;
  *(v4bf*)(Kb + i) = ko;
  float4 z = {0.f, 0.f, 0.f, 0.f};
  *(float4*)(outz + i) = z;  // out = 16*2048*64 = 2M floats = 2048*256*4
  if (j < (size_t)16 * LSEQ) Lz[j] = 0.f;
}

// ---- K1: Lsum[b,k] += sum_q mask*exp(S), swapped orientation ---------------
// Grid: b(16) x qc(4) x kt(32); XCD = kt%8 -> 2MB mask col-slice per XCD L2.
// S[k'][q] = mfma(A=K, B=Q): row(quad*4+r)=k', col(n)=q. Lane-resident csum
// over its 16 k'; mask = float4 along k. Q staged via global_load_lds (dbuf).
__global__ __launch_bounds__(256, 4) void stats_k(const __bf16* __restrict__ Qb,
                                                  const __bf16* __restrict__ Kb,
                                                  const float* __restrict__ mask,
                                                  float* __restrict__ Lsum) {
  const int bx = blockIdx.x;
  const int b = bx >> 7;
  const int qc = (bx >> 5) & 3;
  const int k0 = (bx & 31) * 64;
  const int tid = threadIdx.x;
  const int w = tid >> 6, lane = tid & 63;
  const int quad = lane >> 4, n = lane & 15;

  __shared__ __align__(16) __bf16 Qt[2][64 * 64];
  __shared__ float psum[4][64];

#define STAGE_Q(buf, q0s)                                                        \
  {                                                                              \
    _Pragma("unroll") for (int i = 0; i < 2; ++i) {                              \
      int s = (w * 2 + i) * 64 + lane;                                           \
      int row = s >> 3, gc = (s & 7) ^ (row & 7);                                \
      gl_lds16(Qb + ((size_t)b * LSEQ + (q0s) + row) * DHEAD + gc * 8,           \
               &Qt[buf][s * 8]);                                                 \
    }                                                                            \
  }

  // persistent A=K fragments: lane n -> K row k0+sub*16+n, kd-chunk quad
  v8bf ak[4][2];
#pragma unroll
  for (int sub = 0; sub < 4; ++sub)
#pragma unroll
    for (int dh = 0; dh < 2; ++dh)
      ak[sub][dh] = *(const v8bf*)(Kb + ((size_t)b * LSEQ + k0 + sub * 16 + n) * DHEAD +
                                   dh * 32 + quad * 8);

  float csum[4][4];
#pragma unroll
  for (int sub = 0; sub < 4; ++sub)
#pragma unroll
    for (int r = 0; r < 4; ++r) csum[sub][r] = 0.f;

  const int qbeg = qc * 512;
  STAGE_Q(0, qbeg);
  v4f m4[4], nm[4];
#pragma unroll
  for (int sub = 0; sub < 4; ++sub)
    m4[sub] = *(const v4f*)(mask + (size_t)(qbeg + w * 16 + n) * LSEQ + k0 + sub * 16 +
                            quad * 4);
  __syncthreads();

  int cur = 0;
#pragma unroll 1
  for (int ks = 0; ks < 8; ++ks) {
    const int qs = qbeg + ks * 64;
    if (ks < 7) {
      STAGE_Q(cur ^ 1, qs + 64);  // in flight across compute; drained at barrier
#pragma unroll
      for (int sub = 0; sub < 4; ++sub)
        nm[sub] = *(const v4f*)(mask + (size_t)(qs + 64 + w * 16 + n) * LSEQ + k0 +
                                sub * 16 + quad * 4);
    }
    // B=Q fragments from current buffer (XOR-deswizzled b128 reads)
    const int qr = w * 16 + n;
    v8bf bq[2];
#pragma unroll
    for (int dh = 0; dh < 2; ++dh)
      bq[dh] = *(const v8bf*)&Qt[cur][qr * 64 + ((dh * 4 + quad) ^ (qr & 7)) * 8];

#pragma unroll
    for (int sub = 0; sub < 4; ++sub) {
      v4f c = {0.f, 0.f, 0.f, 0.f};
      c = MFMA16(ak[sub][0], bq[0], c);
      c = MFMA16(ak[sub][1], bq[1], c);
#pragma unroll
      for (int r = 0; r < 4; ++r) csum[sub][r] += m4[sub][r] * __expf(c[r]);
    }
    __syncthreads();  // drains stage vmcnt + all lgkm; publishes Qt[cur^1]
    if (ks < 7) {
#pragma unroll
      for (int sub = 0; sub < 4; ++sub) m4[sub] = nm[sub];
    }
    cur ^= 1;
  }
#undef STAGE_Q

  // csum[sub][r] is the partial colsum for k'=sub*16+quad*4+r over this wave's
  // q (16 lanes x 8 steps). Reduce over n (lane bits 0..3), then over waves.
#pragma unroll
  for (int sub = 0; sub < 4; ++sub)
#pragma unroll
    for (int r = 0; r < 4; ++r) {
      float v = csum[sub][r];
      v += __shfl_xor(v, 1);
      v += __shfl_xor(v, 2);
      v += __shfl_xor(v, 4);
      v += __shfl_xor(v, 8);
      if (n == 0) psum[w][sub * 16 + quad * 4 + r] = v;
    }
  __syncthreads();
  if (tid < 64) {
    float s = psum[0][tid] + psum[1][tid] + psum[2][tid] + psum[3][tid];
    unsafeAtomicAdd(&Lsum[(size_t)b * LSEQ + k0 + tid], s);
  }
}

// ---- K2: Vts[b][v][k] = bf16(V[b][k][v] / L[b][k]) --------------------------
__global__ __launch_bounds__(256) void vtrans_k(const float* __restrict__ V,
                                                const float* __restrict__ Lsum,
                                                __bf16* __restrict__ Vts) {
  const int b = blockIdx.x >> 6;
  const int k0 = (blockIdx.x & 63) * 32;
  const int tid = threadIdx.x;
  __shared__ float tile[32][65];
  __shared__ float invl[32];
  if (tid < 32) invl[tid] = 1.0f / Lsum[(size_t)b * LSEQ + k0 + tid];
#pragma unroll
  for (int t = 0; t < 8; ++t) {
    int flat = t * 256 + tid;
    int k = flat >> 6, v = flat & 63;
    tile[k][v] = V[((size_t)b * LSEQ + k0 + k) * DHEAD + v];
  }
  __syncthreads();
#pragma unroll
  for (int t = 0; t < 8; ++t) {
    int flat = t * 256 + tid;
    int v = flat >> 5, k = flat & 31;
    Vts[((size_t)b * DHEAD + v) * LSEQ + k0 + k] = (__bf16)(tile[k][v] * invl[k]);
  }
}

// ---- K3: O += P @ Vts; swapped QK^T, natural PV, dbuf pipeline --------------
// Grid: b(16) x kc(4) x qt(32); XCD = qt%8: 2MB mask row-slice per XCD L2, and
// all kc partials of a q-tile land on the same XCD (out atomics stay in L2).
__global__ __launch_bounds__(256, 3) void attn_k(const __bf16* __restrict__ Qb,
                                                 const __bf16* __restrict__ Kb,
                                                 const __bf16* __restrict__ Vts,
                                                 const float* __restrict__ mask,
                                                 float* __restrict__ out) {
  const int bx = blockIdx.x;
  const int b = bx >> 7;
  const int kc = (bx >> 5) & 3;
  const int q0 = (bx & 31) * 64;
  const int tid = threadIdx.x;
  const int w = tid >> 6, lane = tid & 63;
  const int quad = lane >> 4, n = lane & 15;

  __shared__ __align__(16) __bf16 Kt[2][64 * 64];
  __shared__ __align__(16) __bf16 Vt[2][64 * 64];
  __shared__ __align__(16) __bf16 Pt[64][72];  // +8 pad: b64/b128 low-conflict

#define STAGE_KV(buf, kb2)                                                       \
  {                                                                              \
    _Pragma("unroll") for (int i = 0; i < 2; ++i) {                              \
      int s = (w * 2 + i) * 64 + lane;                                           \
      int row = s >> 3, gc = (s & 7) ^ (row & 7);                                \
      gl_lds16(Kb + ((size_t)b * LSEQ + (kb2) + row) * DHEAD + gc * 8,           \
               &Kt[buf][s * 8]);                                                 \
      gl_lds16(Vts + ((size_t)b * DHEAD + row) * LSEQ + (kb2) + gc * 8,          \
               &Vt[buf][s * 8]);                                                 \
    }                                                                            \
  }

  const int qg = q0 + w * 16 + n;  // this lane's q for QK^T (C column)

  // persistent B=Q fragments (loaded once; Qb already scaled by 1/8)
  v8bf bq[2];
#pragma unroll
  for (int dh = 0; dh < 2; ++dh)
    bq[dh] = *(const v8bf*)(Qb + ((size_t)b * LSEQ + qg) * DHEAD + dh * 32 + quad * 8);

  v4f acc[4];
#pragma unroll
  for (int vs = 0; vs < 4; ++vs) acc[vs] = (v4f){0.f, 0.f, 0.f, 0.f};

  const int kbeg = kc * 512;
  STAGE_KV(0, kbeg);
  v4f m4[4], nm[4];
#pragma unroll
  for (int sub = 0; sub < 4; ++sub)
    m4[sub] = *(const v4f*)(mask + (size_t)qg * LSEQ + kbeg + sub * 16 + quad * 4);
  __syncthreads();

  int cur = 0;
#pragma unroll 1
  for (int ks = 0; ks < 8; ++ks) {
    const int kb = kbeg + ks * 64;
    if (ks < 7) {
      STAGE_KV(cur ^ 1, kb + 64);  // in flight under QK^T+PV; drained at barrier
#pragma unroll
      for (int sub = 0; sub < 4; ++sub)
        nm[sub] =
            *(const v4f*)(mask + (size_t)qg * LSEQ + kb + 64 + sub * 16 + quad * 4);
    }

    // QK^T swapped: S[k'][q]; P = mask*exp -> v4bf write to Pt[q][k']
#pragma unroll
    for (int sub = 0; sub < 4; ++sub) {
      const int kr = sub * 16 + n;
      v8bf a0 = *(const v8bf*)&Kt[cur][kr * 64 + ((quad) ^ (kr & 7)) * 8];
      v8bf a1 = *(const v8bf*)&Kt[cur][kr * 64 + ((4 + quad) ^ (kr & 7)) * 8];
      v4f c = {0.f, 0.f, 0.f, 0.f};
      c = MFMA16(a0, bq[0], c);
      c = MFMA16(a1, bq[1], c);
      v4bf pv;
#pragma unroll
      for (int r = 0; r < 4; ++r) pv[r] = (__bf16)(m4[sub][r] * __expf(c[r]));
      *(v4bf*)&Pt[w * 16 + n][sub * 16 + quad * 4] = pv;
    }
    __asm__ volatile("s_waitcnt lgkmcnt(0)" ::: "memory");  // own-wave P visible

    // PV natural (R2-verified): A = P rows (own wave), B = Vt
#pragma unroll
    for (int kk = 0; kk < 2; ++kk) {
      v8bf ap = *(const v8bf*)&Pt[w * 16 + n][kk * 32 + quad * 8];
#pragma unroll
      for (int vs = 0; vs < 4; ++vs) {
        const int vr = vs * 16 + n;
        v8bf bv = *(const v8bf*)&Vt[cur][vr * 64 + ((kk * 4 + quad) ^ (vr & 7)) * 8];
        acc[vs] = MFMA16(ap, bv, acc[vs]);
      }
    }
    __syncthreads();  // drains stage vmcnt + lgkm; publishes next buffers
    if (ks < 7) {
#pragma unroll
      for (int sub = 0; sub < 4; ++sub) m4[sub] = nm[sub];
    }
    cur ^= 1;
  }
#undef STAGE_KV

  // C[q][v]: row q = w*16+quad*4+r, col v = vs*16+n (R2-verified epilogue)
#pragma unroll
  for (int vs = 0; vs < 4; ++vs)
#pragma unroll
    for (int r = 0; r < 4; ++r)
      unsafeAtomicAdd(
          &out[((size_t)b * LSEQ + q0 + w * 16 + quad * 4 + r) * DHEAD + vs * 16 + n],
          acc[vs][r]);
}

extern "C" void kernel_launch(void* const* d_in, const int* in_sizes, int n_in,
                              void* d_out, int out_size, void* d_ws, size_t ws_size,
                              hipStream_t stream) {
  const float* Q = (const float*)d_in[0];
  const float* K = (const float*)d_in[1];
  const float* V = (const float*)d_in[2];
  const float* mask = (const float*)d_in[3];
  float* out = (float*)d_out;

  char* ws = (char*)d_ws;
  // ws: Qb 4MiB | Kb 4MiB | Vts 4MiB | Lsum 128KiB  (12.13 MiB)
  __bf16* Qb = (__bf16*)(ws);
  __bf16* Kb = (__bf16*)(ws + (4 << 20));
  __bf16* Vts = (__bf16*)(ws + (8 << 20));
  float* Lsum = (float*)(ws + (12 << 20));
  const size_t need = ((size_t)12 << 20) + (1 << 17);
  if (ws_size < need) return;  // workspace too small — fail loudly (poison out)

  cast_qk<<<2048, 256, 0, stream>>>(Q, K, Qb, Kb, out, Lsum);
  stats_k<<<2048, 256, 0, stream>>>(Qb, Kb, mask, Lsum);
  vtrans_k<<<1024, 256, 0, stream>>>(V, Lsum, Vts);
  attn_k<<<2048, 256, 0, stream>>>(Qb, Kb, Vts, mask, out);
}